// Round 4
// baseline (639.059 us; speedup 1.0000x reference)
//
#include <hip/hip_runtime.h>
#include <hip/hip_bf16.h>
#include <math.h>

typedef unsigned long long u64;

// ---------------- init: deg=1 (self loop), cnt=0 ----------------
__global__ void k_init(float* __restrict__ deg, int* __restrict__ cnt, int n) {
    int i = blockIdx.x * blockDim.x + threadIdx.x;
    if (i < n) { deg[i] = 1.0f; cnt[i] = 0; }
}

// ---------------- count in-degree (dst only) ----------------
__global__ __launch_bounds__(256) void k_cnt(const int* __restrict__ dst, int* __restrict__ cnt, int E) {
    int e = blockIdx.x * 256 + threadIdx.x;
    if (e < E) atomicAdd(&cnt[dst[e]], 1);
}

// ---------------- scan phase 1: per-block (1024 elems) sums ----------------
__global__ __launch_bounds__(256) void k_scan_bsum(const int* __restrict__ cnt, int* __restrict__ bsum, int N) {
    int b = blockIdx.x, t = threadIdx.x;
    int base = b * 1024;
    int s = 0;
#pragma unroll
    for (int q = 0; q < 4; ++q) { int i = base + t * 4 + q; if (i < N) s += cnt[i]; }
    __shared__ int red[256];
    red[t] = s; __syncthreads();
    for (int off = 128; off > 0; off >>= 1) { if (t < off) red[t] += red[t + off]; __syncthreads(); }
    if (t == 0) bsum[b] = red[0];
}

// ---------------- scan phase 2: exclusive scan of <=128 block sums ----------------
__global__ __launch_bounds__(128) void k_scan_top(const int* __restrict__ bsum, int* __restrict__ boff, int nb) {
    __shared__ int a[128], b2[128];
    int t = threadIdx.x;
    int v = (t < nb) ? bsum[t] : 0;
    a[t] = v; __syncthreads();
    int* cur = a; int* nxt = b2;
    for (int off = 1; off < 128; off <<= 1) {
        int x = cur[t];
        if (t >= off) x += cur[t - off];
        nxt[t] = x; __syncthreads();
        int* tmp = cur; cur = nxt; nxt = tmp;
    }
    if (t < nb) boff[t] = cur[t] - v;   // exclusive
}

// ---------------- scan phase 3: write rowptr + cursor ----------------
__global__ __launch_bounds__(256) void k_scan_write(const int* __restrict__ cnt, const int* __restrict__ boff,
                                                    int* __restrict__ rowptr, int* __restrict__ cursor, int N) {
    int b = blockIdx.x, t = threadIdx.x;
    int base = b * 1024;
    int v[4]; int s = 0;
#pragma unroll
    for (int q = 0; q < 4; ++q) { int i = base + t * 4 + q; v[q] = (i < N) ? cnt[i] : 0; s += v[q]; }
    __shared__ int a[256], b2[256];
    a[t] = s; __syncthreads();
    int* cur = a; int* nxt = b2;
    for (int off = 1; off < 256; off <<= 1) {
        int x = cur[t];
        if (t >= off) x += cur[t - off];
        nxt[t] = x; __syncthreads();
        int* tmp = cur; cur = nxt; nxt = tmp;
    }
    int excl = cur[t] - s + boff[b];
#pragma unroll
    for (int q = 0; q < 4; ++q) {
        int i = base + t * 4 + q;
        if (i < N) { rowptr[i] = excl; cursor[i] = excl; excl += v[q]; }
    }
}

// ---------------- edge weight + placement fused ----------------
// 32 lanes/edge: ew = sigmoid(emb@Wv+bv); lane0: deg+=ew, record (ew,src) at cursor[dst]++
__global__ __launch_bounds__(256) void k_edge_ew(
    const float* __restrict__ emb, const float* __restrict__ Wv, const float* __restrict__ bv,
    const int* __restrict__ src, const int* __restrict__ dst,
    float* __restrict__ out_ew, float* __restrict__ deg,
    int* __restrict__ cursor, u64* __restrict__ edat, int E)
{
    int e = blockIdx.x * 8 + (threadIdx.x >> 5);
    if (e >= E) return;
    int l = threadIdx.x & 31;
    const float4 v = ((const float4*)(emb + (size_t)e * 128))[l];
    const float4 w = ((const float4*)Wv)[l];
    float dot = v.x * w.x + v.y * w.y + v.z * w.z + v.w * w.w;
#pragma unroll
    for (int m = 16; m >= 1; m >>= 1) dot += __shfl_xor(dot, m);
    if (l == 0) {
        float x = dot + bv[0];
        float s = 1.0f / (1.0f + expf(-x));
        out_ew[e] = 1.0f - s;
        int d = dst[e];
        atomicAdd(&deg[d], s);
        int p = atomicAdd(&cursor[d], 1);
        edat[p] = ((u64)__float_as_uint(s) << 32) | (unsigned)src[e];
    }
}

// ---------------- Y[n][j] = rsqrt(deg[n]) * sum_k X[n][k] * W[j][k] ----------------
__global__ __launch_bounds__(256) void k_gemm64(
    const float* __restrict__ X, const float* __restrict__ W, const float* __restrict__ deg,
    float* __restrict__ Y, int n)
{
    __shared__ float w[64][64];
    for (int i = threadIdx.x; i < 64 * 64; i += 256) w[i >> 6][i & 63] = W[i];
    __syncthreads();
    int node = blockIdx.x * 256 + threadIdx.x;
    if (node >= n) return;
    float r[64];
    const float4* xr = (const float4*)(X + (size_t)node * 64);
#pragma unroll
    for (int q = 0; q < 16; ++q) {
        float4 v = xr[q];
        r[4 * q] = v.x; r[4 * q + 1] = v.y; r[4 * q + 2] = v.z; r[4 * q + 3] = v.w;
    }
    float ds = rsqrtf(deg[node]);
    float4* yr = (float4*)(Y + (size_t)node * 64);
    for (int j = 0; j < 64; j += 4) {
        float a0 = 0.f, a1 = 0.f, a2 = 0.f, a3 = 0.f;
#pragma unroll
        for (int k = 0; k < 64; ++k) {
            a0 += r[k] * w[j][k];
            a1 += r[k] * w[j + 1][k];
            a2 += r[k] * w[j + 2][k];
            a3 += r[k] * w[j + 3][k];
        }
        float4 acc = {ds * a0, ds * a1, ds * a2, ds * a3};
        yr[j >> 2] = acc;
    }
}

// ---------------- gather-aggregate core: 8-wide batched, branchless ----------------
__device__ __forceinline__ float agg_node(const float* __restrict__ A, const u64* __restrict__ ed,
                                          int c, int lane)
{
    float acc = 0.f;
    int cm1 = (c > 0) ? c - 1 : 0;
    for (int j = 0; j < c; j += 8) {
        u64 e[8];
#pragma unroll
        for (int q = 0; q < 8; ++q) {
            int idx = j + q;
            e[q] = ed[min(idx, cm1)];
        }
        float v[8];
#pragma unroll
        for (int q = 0; q < 8; ++q) {
            int s = (int)(unsigned)(e[q] & 0xffffffffu);
            v[q] = A[(size_t)s * 64 + lane];
        }
#pragma unroll
        for (int q = 0; q < 8; ++q) {
            int idx = j + q;
            float w = (idx < c) ? __uint_as_float((unsigned)(e[q] >> 32)) : 0.f;
            acc += w * v[q];
        }
    }
    return acc;
}

// ---------------- layer-1 aggregate + self-loop + bias + ReLU ----------------
__global__ __launch_bounds__(256) void k_agg1(
    const float* __restrict__ A, const int* __restrict__ rowptr, const int* __restrict__ cnt,
    const u64* __restrict__ edat, const float* __restrict__ deg,
    const float* __restrict__ b1, float* __restrict__ H, int N)
{
    int node = blockIdx.x * 4 + (threadIdx.x >> 6);
    if (node >= N) return;
    int lane = threadIdx.x & 63;
    float acc = agg_node(A, edat + rowptr[node], cnt[node], lane);
    float dsd = rsqrtf(deg[node]);
    float h = dsd * (acc + A[(size_t)node * 64 + lane]) + b1[lane];
    H[(size_t)node * 64 + lane] = fmaxf(h, 0.f);
}

// ---------------- layer-2 aggregate fused with classifier + softmax ----------------
__global__ __launch_bounds__(256) void k_agg2_final(
    const float* __restrict__ A, const int* __restrict__ rowptr, const int* __restrict__ cnt,
    const u64* __restrict__ edat, const float* __restrict__ deg,
    const float* __restrict__ b2, const float* __restrict__ labels,
    const float* __restrict__ Wc, const float* __restrict__ bc,
    float* __restrict__ out, int N)
{
    int node = blockIdx.x * 4 + (threadIdx.x >> 6);
    if (node >= N) return;
    int lane = threadIdx.x & 63;
    float acc = agg_node(A, edat + rowptr[node], cnt[node], lane);
    float dsd = rsqrtf(deg[node]);
    float h = dsd * (acc + A[(size_t)node * 64 + lane]) + b2[lane];
    float p0 = h * Wc[lane];        // Wc row 0 (width 65)
    float p1 = h * Wc[65 + lane];   // Wc row 1
#pragma unroll
    for (int mm = 1; mm < 64; mm <<= 1) {
        p0 += __shfl_xor(p0, mm);
        p1 += __shfl_xor(p1, mm);
    }
    if (lane == 0) {
        float lab = labels[node];
        float l0 = p0 + lab * Wc[64] + bc[0];
        float l1 = p1 + lab * Wc[65 + 64] + bc[1];
        float mx = fmaxf(l0, l1);
        float e0 = expf(l0 - mx), e1 = expf(l1 - mx);
        float inv = 1.0f / (e0 + e1);
        out[2 * (size_t)node]     = e0 * inv;
        out[2 * (size_t)node + 1] = e1 * inv;
    }
}

extern "C" void kernel_launch(void* const* d_in, const int* in_sizes, int n_in,
                              void* d_out, int out_size, void* d_ws, size_t ws_size,
                              hipStream_t stream)
{
    const float* emb      = (const float*)d_in[0];
    const float* features = (const float*)d_in[1];
    const float* labels   = (const float*)d_in[2];
    const float* Wv       = (const float*)d_in[3];
    const float* bv       = (const float*)d_in[4];
    const float* W1       = (const float*)d_in[5];
    const float* b1       = (const float*)d_in[6];
    const float* W2       = (const float*)d_in[7];
    const float* b2       = (const float*)d_in[8];
    const float* Wc       = (const float*)d_in[9];
    const float* bc       = (const float*)d_in[10];
    const int*   eidx     = (const int*)d_in[11];

    const int E = in_sizes[11] / 2;   // 1600000
    const int N = in_sizes[1] / 64;   // 100000
    const int* src = eidx;
    const int* dst = eidx + E;

    float* out      = (float*)d_out;
    float* out_sens = out;                  // N*2
    float* out_ew   = out + 2 * (size_t)N;  // E

    // workspace layout (4B units):
    // deg[N] | A[N*64] | H[N*64] | cnt[N] | rowptr[N] | cursor[N] | bsum[128] | boff[128] | edat[E u64]
    float* deg    = (float*)d_ws;
    float* A      = deg + N;
    float* H      = A + (size_t)N * 64;
    int*   cnt    = (int*)(H + (size_t)N * 64);
    int*   rowptr = cnt + N;
    int*   cursor = rowptr + N;
    int*   bsum   = cursor + N;
    int*   boff   = bsum + 128;
    u64*   edat   = (u64*)(boff + 128);   // even float offset -> 8B aligned

    const int NB = (N + 1023) / 1024;   // 98 <= 128

    // CSR skeleton first (so edge_ew can place records directly)
    k_init<<<(N + 255) / 256, 256, 0, stream>>>(deg, cnt, N);
    k_cnt<<<(E + 255) / 256, 256, 0, stream>>>(dst, cnt, E);
    k_scan_bsum<<<NB, 256, 0, stream>>>(cnt, bsum, N);
    k_scan_top<<<1, 128, 0, stream>>>(bsum, boff, NB);
    k_scan_write<<<NB, 256, 0, stream>>>(cnt, boff, rowptr, cursor, N);

    // heavy pass: ew + deg + record placement
    k_edge_ew<<<(E + 7) / 8, 256, 0, stream>>>(emb, Wv, bv, src, dst, out_ew, deg, cursor, edat, E);

    // layer 1: A = dis * (X@W1^T) ; H = relu(dis_d*(agg + A[d]) + b1)
    k_gemm64<<<(N + 255) / 256, 256, 0, stream>>>(features, W1, deg, A, N);
    k_agg1<<<(N + 3) / 4, 256, 0, stream>>>(A, rowptr, cnt, edat, deg, b1, H, N);

    // layer 2 + classifier + softmax
    k_gemm64<<<(N + 255) / 256, 256, 0, stream>>>(H, W2, deg, A, N);
    k_agg2_final<<<(N + 3) / 4, 256, 0, stream>>>(A, rowptr, cnt, edat, deg, b2,
                                                  labels, Wc, bc, out_sens, N);
}

// Round 5
// 608.347 us; speedup vs baseline: 1.0505x; 1.0505x over previous
//
#include <hip/hip_runtime.h>
#include <hip/hip_bf16.h>
#include <hip/hip_fp16.h>
#include <math.h>

typedef unsigned long long u64;

// ---------------- init: deg=1 (self loop), cnt=0 ----------------
__global__ void k_init(float* __restrict__ deg, int* __restrict__ cnt, int n) {
    int i = blockIdx.x * blockDim.x + threadIdx.x;
    if (i < n) { deg[i] = 1.0f; cnt[i] = 0; }
}

// ---------------- edge weight: ew = sigmoid(emb_cat @ Wv^T + bv) ----------------
// 32 lanes/edge; lane0: store 1-ew, bump weighted degree + in-degree count.
__global__ __launch_bounds__(256) void k_edge_ew(
    const float* __restrict__ emb, const float* __restrict__ Wv, const float* __restrict__ bv,
    const int* __restrict__ dst, float* __restrict__ out_ew,
    float* __restrict__ deg, int* __restrict__ cnt, int E)
{
    int e = blockIdx.x * 8 + (threadIdx.x >> 5);
    if (e >= E) return;
    int l = threadIdx.x & 31;
    const float4 v = ((const float4*)(emb + (size_t)e * 128))[l];
    const float4 w = ((const float4*)Wv)[l];
    float dot = v.x * w.x + v.y * w.y + v.z * w.z + v.w * w.w;
#pragma unroll
    for (int m = 16; m >= 1; m >>= 1) dot += __shfl_xor(dot, m);
    if (l == 0) {
        float x = dot + bv[0];
        float s = 1.0f / (1.0f + expf(-x));
        out_ew[e] = 1.0f - s;
        int d = dst[e];
        atomicAdd(&deg[d], s);
        atomicAdd(&cnt[d], 1);
    }
}

// ---------------- scan phase 1: per-block (1024 elems) sums ----------------
__global__ __launch_bounds__(256) void k_scan_bsum(const int* __restrict__ cnt, int* __restrict__ bsum, int N) {
    int b = blockIdx.x, t = threadIdx.x;
    int base = b * 1024;
    int s = 0;
#pragma unroll
    for (int q = 0; q < 4; ++q) { int i = base + t * 4 + q; if (i < N) s += cnt[i]; }
    __shared__ int red[256];
    red[t] = s; __syncthreads();
    for (int off = 128; off > 0; off >>= 1) { if (t < off) red[t] += red[t + off]; __syncthreads(); }
    if (t == 0) bsum[b] = red[0];
}

// ---------------- scan phase 2: exclusive scan of <=128 block sums ----------------
__global__ __launch_bounds__(128) void k_scan_top(const int* __restrict__ bsum, int* __restrict__ boff, int nb) {
    __shared__ int a[128], b2[128];
    int t = threadIdx.x;
    int v = (t < nb) ? bsum[t] : 0;
    a[t] = v; __syncthreads();
    int* cur = a; int* nxt = b2;
    for (int off = 1; off < 128; off <<= 1) {
        int x = cur[t];
        if (t >= off) x += cur[t - off];
        nxt[t] = x; __syncthreads();
        int* tmp = cur; cur = nxt; nxt = tmp;
    }
    if (t < nb) boff[t] = cur[t] - v;   // exclusive
}

// ---------------- scan phase 3: write rowptr + cursor ----------------
__global__ __launch_bounds__(256) void k_scan_write(const int* __restrict__ cnt, const int* __restrict__ boff,
                                                    int* __restrict__ rowptr, int* __restrict__ cursor, int N) {
    int b = blockIdx.x, t = threadIdx.x;
    int base = b * 1024;
    int v[4]; int s = 0;
#pragma unroll
    for (int q = 0; q < 4; ++q) { int i = base + t * 4 + q; v[q] = (i < N) ? cnt[i] : 0; s += v[q]; }
    __shared__ int a[256], b2[256];
    a[t] = s; __syncthreads();
    int* cur = a; int* nxt = b2;
    for (int off = 1; off < 256; off <<= 1) {
        int x = cur[t];
        if (t >= off) x += cur[t - off];
        nxt[t] = x; __syncthreads();
        int* tmp = cur; cur = nxt; nxt = tmp;
    }
    int excl = cur[t] - s + boff[b];
#pragma unroll
    for (int q = 0; q < 4; ++q) {
        int i = base + t * 4 + q;
        if (i < N) { rowptr[i] = excl; cursor[i] = excl; excl += v[q]; }
    }
}

// ---------------- placement: dst-sorted packed (ew, src) records ----------------
// one thread per edge -> hundreds of independent scatters in flight per block
__global__ __launch_bounds__(256) void k_place(const int* __restrict__ src, const int* __restrict__ dst,
                                               const float* __restrict__ out_ew,
                                               int* __restrict__ cursor, u64* __restrict__ edat, int E) {
    int e = blockIdx.x * 256 + threadIdx.x;
    if (e >= E) return;
    int s = src[e], d = dst[e];
    float w = 1.0f - out_ew[e];
    int p = atomicAdd(&cursor[d], 1);
    edat[p] = ((u64)__float_as_uint(w) << 32) | (unsigned)s;
}

// ---------------- Y[n][j] = half( rsqrt(deg[n]) * sum_k X[n][k] * W[j][k] ) ----------------
__global__ __launch_bounds__(256) void k_gemm64h(
    const float* __restrict__ X, const float* __restrict__ W, const float* __restrict__ deg,
    __half* __restrict__ Y, int n)
{
    __shared__ float w[64][64];
    for (int i = threadIdx.x; i < 64 * 64; i += 256) w[i >> 6][i & 63] = W[i];
    __syncthreads();
    int node = blockIdx.x * 256 + threadIdx.x;
    if (node >= n) return;
    float r[64];
    const float4* xr = (const float4*)(X + (size_t)node * 64);
#pragma unroll
    for (int q = 0; q < 16; ++q) {
        float4 v = xr[q];
        r[4 * q] = v.x; r[4 * q + 1] = v.y; r[4 * q + 2] = v.z; r[4 * q + 3] = v.w;
    }
    float ds = rsqrtf(deg[node]);
    uint2* yr = (uint2*)(Y + (size_t)node * 64);
    for (int j = 0; j < 64; j += 4) {
        float a0 = 0.f, a1 = 0.f, a2 = 0.f, a3 = 0.f;
#pragma unroll
        for (int k = 0; k < 64; ++k) {
            a0 += r[k] * w[j][k];
            a1 += r[k] * w[j + 1][k];
            a2 += r[k] * w[j + 2][k];
            a3 += r[k] * w[j + 3][k];
        }
        __half2 h01 = __floats2half2_rn(ds * a0, ds * a1);
        __half2 h23 = __floats2half2_rn(ds * a2, ds * a3);
        uint2 pk;
        pk.x = *(unsigned*)&h01;
        pk.y = *(unsigned*)&h23;
        yr[j >> 2] = pk;
    }
}

// ---------------- gather-aggregate core: 8-wide batched, branchless, fp16 source ----------------
__device__ __forceinline__ float agg_node(const __half* __restrict__ A, const u64* __restrict__ ed,
                                          int c, int lane)
{
    float acc = 0.f;
    int cm1 = (c > 0) ? c - 1 : 0;
    for (int j = 0; j < c; j += 8) {
        u64 e[8];
#pragma unroll
        for (int q = 0; q < 8; ++q) {
            int idx = j + q;
            e[q] = ed[min(idx, cm1)];
        }
        float v[8];
#pragma unroll
        for (int q = 0; q < 8; ++q) {
            int s = (int)(unsigned)(e[q] & 0xffffffffu);
            v[q] = __half2float(A[(size_t)s * 64 + lane]);
        }
#pragma unroll
        for (int q = 0; q < 8; ++q) {
            int idx = j + q;
            float w = (idx < c) ? __uint_as_float((unsigned)(e[q] >> 32)) : 0.f;
            acc += w * v[q];
        }
    }
    return acc;
}

// ---------------- layer-1 aggregate + self-loop + bias + ReLU ----------------
__global__ __launch_bounds__(256) void k_agg1(
    const __half* __restrict__ A, const int* __restrict__ rowptr, const int* __restrict__ cnt,
    const u64* __restrict__ edat, const float* __restrict__ deg,
    const float* __restrict__ b1, float* __restrict__ H, int N)
{
    int node = blockIdx.x * 4 + (threadIdx.x >> 6);
    if (node >= N) return;
    int lane = threadIdx.x & 63;
    float acc = agg_node(A, edat + rowptr[node], cnt[node], lane);
    float dsd = rsqrtf(deg[node]);
    float self = __half2float(A[(size_t)node * 64 + lane]);
    float h = dsd * (acc + self) + b1[lane];
    H[(size_t)node * 64 + lane] = fmaxf(h, 0.f);
}

// ---------------- layer-2 aggregate fused with classifier + softmax ----------------
__global__ __launch_bounds__(256) void k_agg2_final(
    const __half* __restrict__ A, const int* __restrict__ rowptr, const int* __restrict__ cnt,
    const u64* __restrict__ edat, const float* __restrict__ deg,
    const float* __restrict__ b2, const float* __restrict__ labels,
    const float* __restrict__ Wc, const float* __restrict__ bc,
    float* __restrict__ out, int N)
{
    int node = blockIdx.x * 4 + (threadIdx.x >> 6);
    if (node >= N) return;
    int lane = threadIdx.x & 63;
    float acc = agg_node(A, edat + rowptr[node], cnt[node], lane);
    float dsd = rsqrtf(deg[node]);
    float self = __half2float(A[(size_t)node * 64 + lane]);
    float h = dsd * (acc + self) + b2[lane];
    float p0 = h * Wc[lane];        // Wc row 0 (width 65)
    float p1 = h * Wc[65 + lane];   // Wc row 1
#pragma unroll
    for (int mm = 1; mm < 64; mm <<= 1) {
        p0 += __shfl_xor(p0, mm);
        p1 += __shfl_xor(p1, mm);
    }
    if (lane == 0) {
        float lab = labels[node];
        float l0 = p0 + lab * Wc[64] + bc[0];
        float l1 = p1 + lab * Wc[65 + 64] + bc[1];
        float mx = fmaxf(l0, l1);
        float e0 = expf(l0 - mx), e1 = expf(l1 - mx);
        float inv = 1.0f / (e0 + e1);
        out[2 * (size_t)node]     = e0 * inv;
        out[2 * (size_t)node + 1] = e1 * inv;
    }
}

extern "C" void kernel_launch(void* const* d_in, const int* in_sizes, int n_in,
                              void* d_out, int out_size, void* d_ws, size_t ws_size,
                              hipStream_t stream)
{
    const float* emb      = (const float*)d_in[0];
    const float* features = (const float*)d_in[1];
    const float* labels   = (const float*)d_in[2];
    const float* Wv       = (const float*)d_in[3];
    const float* bv       = (const float*)d_in[4];
    const float* W1       = (const float*)d_in[5];
    const float* b1       = (const float*)d_in[6];
    const float* W2       = (const float*)d_in[7];
    const float* b2       = (const float*)d_in[8];
    const float* Wc       = (const float*)d_in[9];
    const float* bc       = (const float*)d_in[10];
    const int*   eidx     = (const int*)d_in[11];

    const int E = in_sizes[11] / 2;   // 1600000
    const int N = in_sizes[1] / 64;   // 100000
    const int* src = eidx;
    const int* dst = eidx + E;

    float* out      = (float*)d_out;
    float* out_sens = out;                  // N*2
    float* out_ew   = out + 2 * (size_t)N;  // E

    // workspace layout (4B units):
    // deg[N] | Ah[N*64 halves = N*32 u32] | H[N*64] | cnt[N] | rowptr[N] | cursor[N]
    // | bsum[128] | boff[128] | edat[E u64]
    float*  deg    = (float*)d_ws;
    __half* Ah     = (__half*)(deg + N);
    float*  H      = (float*)(Ah + (size_t)N * 64);
    int*    cnt    = (int*)(H + (size_t)N * 64);
    int*    rowptr = cnt + N;
    int*    cursor = rowptr + N;
    int*    bsum   = cursor + N;
    int*    boff   = bsum + 128;
    u64*    edat   = (u64*)(boff + 128);   // even 4B-unit offset -> 8B aligned

    const int NB = (N + 1023) / 1024;   // 98 <= 128

    k_init<<<(N + 255) / 256, 256, 0, stream>>>(deg, cnt, N);

    // heavy streaming pass (kept pure): ew + deg + cnt
    k_edge_ew<<<(E + 7) / 8, 256, 0, stream>>>(emb, Wv, bv, dst, out_ew, deg, cnt, E);

    // CSR build (dst-sorted records)
    k_scan_bsum<<<NB, 256, 0, stream>>>(cnt, bsum, N);
    k_scan_top<<<1, 128, 0, stream>>>(bsum, boff, NB);
    k_scan_write<<<NB, 256, 0, stream>>>(cnt, boff, rowptr, cursor, N);
    k_place<<<(E + 255) / 256, 256, 0, stream>>>(src, dst, out_ew, cursor, edat, E);

    // layer 1: Ah = half(dis * (X@W1^T)) ; H = relu(dis_d*(agg + Ah[d]) + b1)
    k_gemm64h<<<(N + 255) / 256, 256, 0, stream>>>(features, W1, deg, Ah, N);
    k_agg1<<<(N + 3) / 4, 256, 0, stream>>>(Ah, rowptr, cnt, edat, deg, b1, H, N);

    // layer 2 + classifier + softmax
    k_gemm64h<<<(N + 255) / 256, 256, 0, stream>>>(H, W2, deg, Ah, N);
    k_agg2_final<<<(N + 3) / 4, 256, 0, stream>>>(Ah, rowptr, cnt, edat, deg, b2,
                                                  labels, Wc, bc, out_sens, N);
}

// Round 6
// 550.415 us; speedup vs baseline: 1.1610x; 1.1053x over previous
//
#include <hip/hip_runtime.h>
#include <hip/hip_bf16.h>
#include <hip/hip_fp16.h>
#include <math.h>

typedef unsigned long long u64;

// ---------------- init: deg=1 (self loop), cnt=0 ----------------
__global__ void k_init(float* __restrict__ deg, int* __restrict__ cnt, int n) {
    int i = blockIdx.x * blockDim.x + threadIdx.x;
    if (i < n) { deg[i] = 1.0f; cnt[i] = 0; }
}

// ---------------- count in-degree (dst only) ----------------
__global__ __launch_bounds__(256) void k_cnt(const int* __restrict__ dst, int* __restrict__ cnt, int E) {
    int e = blockIdx.x * 256 + threadIdx.x;
    if (e < E) atomicAdd(&cnt[dst[e]], 1);
}

// ---------------- edge weight: ew = sigmoid(emb_cat @ Wv^T + bv) ----------------
// 32-lane group handles 4 consecutive edges (4 independent 512B loads in flight).
__global__ __launch_bounds__(256) void k_edge_ew(
    const float* __restrict__ emb, const float* __restrict__ Wv, const float* __restrict__ bv,
    const int* __restrict__ dst, float* __restrict__ out_ew,
    float* __restrict__ deg, int E)
{
    int grp = blockIdx.x * 8 + (threadIdx.x >> 5);
    int base = grp * 4;
    if (base >= E) return;
    int l = threadIdx.x & 31;
    const float4* embp = (const float4*)emb;
    const float4 w = ((const float4*)Wv)[l];
    float dot[4];
#pragma unroll
    for (int q = 0; q < 4; ++q) {
        const float4 v = embp[(size_t)(base + q) * 32 + l];   // E % 4 == 0
        dot[q] = v.x * w.x + v.y * w.y + v.z * w.z + v.w * w.w;
    }
#pragma unroll
    for (int m = 16; m >= 1; m >>= 1) {
#pragma unroll
        for (int q = 0; q < 4; ++q) dot[q] += __shfl_xor(dot[q], m);
    }
    if (l == 0) {
        float bv0 = bv[0];
        float s[4];
#pragma unroll
        for (int q = 0; q < 4; ++q) {
            s[q] = 1.0f / (1.0f + expf(-(dot[q] + bv0)));
            atomicAdd(&deg[dst[base + q]], s[q]);
        }
        float4 o = {1.0f - s[0], 1.0f - s[1], 1.0f - s[2], 1.0f - s[3]};
        ((float4*)out_ew)[grp] = o;
    }
}

// ---------------- scan phase 1: per-block (1024 elems) sums ----------------
__global__ __launch_bounds__(256) void k_scan_bsum(const int* __restrict__ cnt, int* __restrict__ bsum, int N) {
    int b = blockIdx.x, t = threadIdx.x;
    int base = b * 1024;
    int s = 0;
#pragma unroll
    for (int q = 0; q < 4; ++q) { int i = base + t * 4 + q; if (i < N) s += cnt[i]; }
    __shared__ int red[256];
    red[t] = s; __syncthreads();
    for (int off = 128; off > 0; off >>= 1) { if (t < off) red[t] += red[t + off]; __syncthreads(); }
    if (t == 0) bsum[b] = red[0];
}

// ---------------- scan phase 2: exclusive scan of <=128 block sums ----------------
__global__ __launch_bounds__(128) void k_scan_top(const int* __restrict__ bsum, int* __restrict__ boff, int nb) {
    __shared__ int a[128], b2[128];
    int t = threadIdx.x;
    int v = (t < nb) ? bsum[t] : 0;
    a[t] = v; __syncthreads();
    int* cur = a; int* nxt = b2;
    for (int off = 1; off < 128; off <<= 1) {
        int x = cur[t];
        if (t >= off) x += cur[t - off];
        nxt[t] = x; __syncthreads();
        int* tmp = cur; cur = nxt; nxt = tmp;
    }
    if (t < nb) boff[t] = cur[t] - v;   // exclusive
}

// ---------------- scan phase 3: write rowptr + cursor ----------------
__global__ __launch_bounds__(256) void k_scan_write(const int* __restrict__ cnt, const int* __restrict__ boff,
                                                    int* __restrict__ rowptr, int* __restrict__ cursor, int N) {
    int b = blockIdx.x, t = threadIdx.x;
    int base = b * 1024;
    int v[4]; int s = 0;
#pragma unroll
    for (int q = 0; q < 4; ++q) { int i = base + t * 4 + q; v[q] = (i < N) ? cnt[i] : 0; s += v[q]; }
    __shared__ int a[256], b2[256];
    a[t] = s; __syncthreads();
    int* cur = a; int* nxt = b2;
    for (int off = 1; off < 256; off <<= 1) {
        int x = cur[t];
        if (t >= off) x += cur[t - off];
        nxt[t] = x; __syncthreads();
        int* tmp = cur; cur = nxt; nxt = tmp;
    }
    int excl = cur[t] - s + boff[b];
#pragma unroll
    for (int q = 0; q < 4; ++q) {
        int i = base + t * 4 + q;
        if (i < N) { rowptr[i] = excl; cursor[i] = excl; excl += v[q]; }
    }
}

// ---------------- placement: dst-sorted packed (ew, src) records ----------------
__global__ __launch_bounds__(256) void k_place(const int* __restrict__ src, const int* __restrict__ dst,
                                               const float* __restrict__ out_ew,
                                               int* __restrict__ cursor, u64* __restrict__ edat, int E) {
    int e = blockIdx.x * 256 + threadIdx.x;
    if (e >= E) return;
    int s = src[e], d = dst[e];
    float w = 1.0f - out_ew[e];
    int p = atomicAdd(&cursor[d], 1);
    edat[p] = ((u64)__float_as_uint(w) << 32) | (unsigned)s;
}

// ---------------- Y[n][j] = half( rsqrt(deg[n]) * sum_k X[n][k] * W[j][k] ) ----------------
__global__ __launch_bounds__(256) void k_gemm64h(
    const float* __restrict__ X, const float* __restrict__ W, const float* __restrict__ deg,
    __half* __restrict__ Y, int n)
{
    __shared__ float w[64][64];
    for (int i = threadIdx.x; i < 64 * 64; i += 256) w[i >> 6][i & 63] = W[i];
    __syncthreads();
    int node = blockIdx.x * 256 + threadIdx.x;
    if (node >= n) return;
    float r[64];
    const float4* xr = (const float4*)(X + (size_t)node * 64);
#pragma unroll
    for (int q = 0; q < 16; ++q) {
        float4 v = xr[q];
        r[4 * q] = v.x; r[4 * q + 1] = v.y; r[4 * q + 2] = v.z; r[4 * q + 3] = v.w;
    }
    float ds = rsqrtf(deg[node]);
    uint2* yr = (uint2*)(Y + (size_t)node * 64);
    for (int j = 0; j < 64; j += 4) {
        float a0 = 0.f, a1 = 0.f, a2 = 0.f, a3 = 0.f;
#pragma unroll
        for (int k = 0; k < 64; ++k) {
            a0 += r[k] * w[j][k];
            a1 += r[k] * w[j + 1][k];
            a2 += r[k] * w[j + 2][k];
            a3 += r[k] * w[j + 3][k];
        }
        __half2 h01 = __floats2half2_rn(ds * a0, ds * a1);
        __half2 h23 = __floats2half2_rn(ds * a2, ds * a3);
        uint2 pk;
        pk.x = *(unsigned*)&h01;
        pk.y = *(unsigned*)&h23;
        yr[j >> 2] = pk;
    }
}

// ---------------- gather-aggregate: 2 edges/iter-pair via half2 lanes ----------------
// lanes 0-31 take even edges, lanes 32-63 odd edges; combine with shfl_xor(32).
// Returns features (2l, 2l+1) where l = lane&31, valid in ALL lanes.
__device__ __forceinline__ float2 agg_node2(const __half2* __restrict__ A2, const u64* __restrict__ ed,
                                            int c, int lane)
{
    int g = lane >> 5;
    int l = lane & 31;
    float2 acc = {0.f, 0.f};
    int cm1 = (c > 0) ? c - 1 : 0;
    for (int jb = 0; jb < c; jb += 16) {
        u64 myrec = ed[min(jb + (lane & 15), cm1)];   // 16 records, coalesced
        u64 rec[8];
#pragma unroll
        for (int q = 0; q < 8; ++q) rec[q] = __shfl(myrec, 2 * q + g);
        unsigned raw[8];
#pragma unroll
        for (int q = 0; q < 8; ++q) {
            int s = (int)(unsigned)(rec[q] & 0xffffffffu);
            raw[q] = *(const unsigned*)&A2[(size_t)s * 32 + l];   // 8 gathers in flight
        }
#pragma unroll
        for (int q = 0; q < 8; ++q) {
            int idx = jb + 2 * q + g;
            float w = (idx < c) ? __uint_as_float((unsigned)(rec[q] >> 32)) : 0.f;
            __half2 hv = *(__half2*)&raw[q];
            float2 v = __half22float2(hv);
            acc.x += w * v.x;
            acc.y += w * v.y;
        }
    }
    acc.x += __shfl_xor(acc.x, 32);
    acc.y += __shfl_xor(acc.y, 32);
    return acc;
}

// ---------------- layer-1 aggregate + self-loop + bias + ReLU ----------------
__global__ __launch_bounds__(256) void k_agg1(
    const __half* __restrict__ A, const int* __restrict__ rowptr, const int* __restrict__ cnt,
    const u64* __restrict__ edat, const float* __restrict__ deg,
    const float* __restrict__ b1, float* __restrict__ H, int N)
{
    int node = blockIdx.x * 4 + (threadIdx.x >> 6);
    if (node >= N) return;
    int lane = threadIdx.x & 63;
    int l = lane & 31;
    const __half2* A2 = (const __half2*)A;
    float2 acc = agg_node2(A2, edat + rowptr[node], cnt[node], lane);
    float dsd = rsqrtf(deg[node]);
    float2 self = __half22float2(A2[(size_t)node * 32 + l]);
    float2 bb = ((const float2*)b1)[l];
    if (lane < 32) {
        float2 h;
        h.x = fmaxf(dsd * (acc.x + self.x) + bb.x, 0.f);
        h.y = fmaxf(dsd * (acc.y + self.y) + bb.y, 0.f);
        ((float2*)(H + (size_t)node * 64))[l] = h;
    }
}

// ---------------- layer-2 aggregate fused with classifier + softmax ----------------
__global__ __launch_bounds__(256) void k_agg2_final(
    const __half* __restrict__ A, const int* __restrict__ rowptr, const int* __restrict__ cnt,
    const u64* __restrict__ edat, const float* __restrict__ deg,
    const float* __restrict__ b2, const float* __restrict__ labels,
    const float* __restrict__ Wc, const float* __restrict__ bc,
    float* __restrict__ out, int N)
{
    int node = blockIdx.x * 4 + (threadIdx.x >> 6);
    if (node >= N) return;
    int lane = threadIdx.x & 63;
    int l = lane & 31;
    const __half2* A2 = (const __half2*)A;
    float2 acc = agg_node2(A2, edat + rowptr[node], cnt[node], lane);
    float dsd = rsqrtf(deg[node]);
    float2 self = __half22float2(A2[(size_t)node * 32 + l]);
    float2 bb = ((const float2*)b2)[l];
    float hx = dsd * (acc.x + self.x) + bb.x;
    float hy = dsd * (acc.y + self.y) + bb.y;
    // classifier: row0 via float2 (aligned), row1 via scalars (odd offset 65)
    float2 wc0 = ((const float2*)Wc)[l];
    float w1x = Wc[65 + 2 * l], w1y = Wc[65 + 2 * l + 1];
    float p0 = hx * wc0.x + hy * wc0.y;
    float p1 = hx * w1x + hy * w1y;
    if (lane >= 32) { p0 = 0.f; p1 = 0.f; }   // avoid double count
#pragma unroll
    for (int mm = 1; mm < 64; mm <<= 1) {
        p0 += __shfl_xor(p0, mm);
        p1 += __shfl_xor(p1, mm);
    }
    if (lane == 0) {
        float lab = labels[node];
        float l0 = p0 + lab * Wc[64] + bc[0];
        float l1 = p1 + lab * Wc[65 + 64] + bc[1];
        float mx = fmaxf(l0, l1);
        float e0 = expf(l0 - mx), e1 = expf(l1 - mx);
        float inv = 1.0f / (e0 + e1);
        out[2 * (size_t)node]     = e0 * inv;
        out[2 * (size_t)node + 1] = e1 * inv;
    }
}

extern "C" void kernel_launch(void* const* d_in, const int* in_sizes, int n_in,
                              void* d_out, int out_size, void* d_ws, size_t ws_size,
                              hipStream_t stream)
{
    const float* emb      = (const float*)d_in[0];
    const float* features = (const float*)d_in[1];
    const float* labels   = (const float*)d_in[2];
    const float* Wv       = (const float*)d_in[3];
    const float* bv       = (const float*)d_in[4];
    const float* W1       = (const float*)d_in[5];
    const float* b1       = (const float*)d_in[6];
    const float* W2       = (const float*)d_in[7];
    const float* b2       = (const float*)d_in[8];
    const float* Wc       = (const float*)d_in[9];
    const float* bc       = (const float*)d_in[10];
    const int*   eidx     = (const int*)d_in[11];

    const int E = in_sizes[11] / 2;   // 1600000
    const int N = in_sizes[1] / 64;   // 100000
    const int* src = eidx;
    const int* dst = eidx + E;

    float* out      = (float*)d_out;
    float* out_sens = out;                  // N*2
    float* out_ew   = out + 2 * (size_t)N;  // E

    // workspace layout (4B units):
    // deg[N] | Ah[N*64 halves] | H[N*64] | cnt[N] | rowptr[N] | cursor[N] | bsum[128] | boff[128] | edat[E u64]
    float*  deg    = (float*)d_ws;
    __half* Ah     = (__half*)(deg + N);
    float*  H      = (float*)(Ah + (size_t)N * 64);
    int*    cnt    = (int*)(H + (size_t)N * 64);
    int*    rowptr = cnt + N;
    int*    cursor = rowptr + N;
    int*    bsum   = cursor + N;
    int*    boff   = bsum + 128;
    u64*    edat   = (u64*)(boff + 128);

    const int NB = (N + 1023) / 1024;   // 98 <= 128

    k_init<<<(N + 255) / 256, 256, 0, stream>>>(deg, cnt, N);
    k_cnt<<<(E + 255) / 256, 256, 0, stream>>>(dst, cnt, E);

    // heavy streaming pass: ew + deg only
    k_edge_ew<<<(E / 4 + 7) / 8, 256, 0, stream>>>(emb, Wv, bv, dst, out_ew, deg, E);

    // CSR build (dst-sorted records)
    k_scan_bsum<<<NB, 256, 0, stream>>>(cnt, bsum, N);
    k_scan_top<<<1, 128, 0, stream>>>(bsum, boff, NB);
    k_scan_write<<<NB, 256, 0, stream>>>(cnt, boff, rowptr, cursor, N);
    k_place<<<(E + 255) / 256, 256, 0, stream>>>(src, dst, out_ew, cursor, edat, E);

    // layer 1
    k_gemm64h<<<(N + 255) / 256, 256, 0, stream>>>(features, W1, deg, Ah, N);
    k_agg1<<<(N + 3) / 4, 256, 0, stream>>>(Ah, rowptr, cnt, edat, deg, b1, H, N);

    // layer 2 + classifier + softmax
    k_gemm64h<<<(N + 255) / 256, 256, 0, stream>>>(H, W2, deg, Ah, N);
    k_agg2_final<<<(N + 3) / 4, 256, 0, stream>>>(Ah, rowptr, cnt, edat, deg, b2,
                                                  labels, Wc, bc, out_sens, N);
}

// Round 7
// 545.065 us; speedup vs baseline: 1.1724x; 1.0098x over previous
//
#include <hip/hip_runtime.h>
#include <hip/hip_bf16.h>
#include <hip/hip_fp16.h>
#include <math.h>

typedef unsigned long long u64;

// ---------------- init: cnt=0 ----------------
__global__ void k_init(int* __restrict__ cnt, int n) {
    int i = blockIdx.x * blockDim.x + threadIdx.x;
    if (i < n) cnt[i] = 0;
}

// ---------------- count in-degree (dst only) ----------------
__global__ __launch_bounds__(256) void k_cnt(const int* __restrict__ dst, int* __restrict__ cnt, int E) {
    int e = blockIdx.x * 256 + threadIdx.x;
    if (e < E) atomicAdd(&cnt[dst[e]], 1);
}

// ---------------- edge weight: PURE STREAM: out_ew = 1 - sigmoid(emb@Wv+bv) ----------------
// 32-lane group handles 4 consecutive edges (4 independent 512B loads in flight). No atomics.
__global__ __launch_bounds__(256) void k_edge_ew(
    const float* __restrict__ emb, const float* __restrict__ Wv, const float* __restrict__ bv,
    float* __restrict__ out_ew, int E)
{
    int grp = blockIdx.x * 8 + (threadIdx.x >> 5);
    int base = grp * 4;
    if (base >= E) return;
    int l = threadIdx.x & 31;
    const float4* embp = (const float4*)emb;
    const float4 w = ((const float4*)Wv)[l];
    float dot[4];
#pragma unroll
    for (int q = 0; q < 4; ++q) {
        const float4 v = embp[(size_t)(base + q) * 32 + l];   // E % 4 == 0
        dot[q] = v.x * w.x + v.y * w.y + v.z * w.z + v.w * w.w;
    }
#pragma unroll
    for (int m = 16; m >= 1; m >>= 1) {
#pragma unroll
        for (int q = 0; q < 4; ++q) dot[q] += __shfl_xor(dot[q], m);
    }
    if (l == 0) {
        float bv0 = bv[0];
        float s[4];
#pragma unroll
        for (int q = 0; q < 4; ++q) s[q] = 1.0f / (1.0f + expf(-(dot[q] + bv0)));
        float4 o = {1.0f - s[0], 1.0f - s[1], 1.0f - s[2], 1.0f - s[3]};
        ((float4*)out_ew)[grp] = o;
    }
}

// ---------------- scan phase 1: per-block (1024 elems) sums ----------------
__global__ __launch_bounds__(256) void k_scan_bsum(const int* __restrict__ cnt, int* __restrict__ bsum, int N) {
    int b = blockIdx.x, t = threadIdx.x;
    int base = b * 1024;
    int s = 0;
#pragma unroll
    for (int q = 0; q < 4; ++q) { int i = base + t * 4 + q; if (i < N) s += cnt[i]; }
    __shared__ int red[256];
    red[t] = s; __syncthreads();
    for (int off = 128; off > 0; off >>= 1) { if (t < off) red[t] += red[t + off]; __syncthreads(); }
    if (t == 0) bsum[b] = red[0];
}

// ---------------- scan phase 2: exclusive scan of <=128 block sums ----------------
__global__ __launch_bounds__(128) void k_scan_top(const int* __restrict__ bsum, int* __restrict__ boff, int nb) {
    __shared__ int a[128], b2[128];
    int t = threadIdx.x;
    int v = (t < nb) ? bsum[t] : 0;
    a[t] = v; __syncthreads();
    int* cur = a; int* nxt = b2;
    for (int off = 1; off < 128; off <<= 1) {
        int x = cur[t];
        if (t >= off) x += cur[t - off];
        nxt[t] = x; __syncthreads();
        int* tmp = cur; cur = nxt; nxt = tmp;
    }
    if (t < nb) boff[t] = cur[t] - v;   // exclusive
}

// ---------------- scan phase 3: write rowptr + cursor ----------------
__global__ __launch_bounds__(256) void k_scan_write(const int* __restrict__ cnt, const int* __restrict__ boff,
                                                    int* __restrict__ rowptr, int* __restrict__ cursor, int N) {
    int b = blockIdx.x, t = threadIdx.x;
    int base = b * 1024;
    int v[4]; int s = 0;
#pragma unroll
    for (int q = 0; q < 4; ++q) { int i = base + t * 4 + q; v[q] = (i < N) ? cnt[i] : 0; s += v[q]; }
    __shared__ int a[256], b2[256];
    a[t] = s; __syncthreads();
    int* cur = a; int* nxt = b2;
    for (int off = 1; off < 256; off <<= 1) {
        int x = cur[t];
        if (t >= off) x += cur[t - off];
        nxt[t] = x; __syncthreads();
        int* tmp = cur; cur = nxt; nxt = tmp;
    }
    int excl = cur[t] - s + boff[b];
#pragma unroll
    for (int q = 0; q < 4; ++q) {
        int i = base + t * 4 + q;
        if (i < N) { rowptr[i] = excl; cursor[i] = excl; excl += v[q]; }
    }
}

// ---------------- placement: dst-sorted packed (ew, src) records ----------------
__global__ __launch_bounds__(256) void k_place(const int* __restrict__ src, const int* __restrict__ dst,
                                               const float* __restrict__ out_ew,
                                               int* __restrict__ cursor, u64* __restrict__ edat, int E) {
    int e = blockIdx.x * 256 + threadIdx.x;
    if (e >= E) return;
    int s = src[e], d = dst[e];
    float w = 1.0f - out_ew[e];
    int p = atomicAdd(&cursor[d], 1);
    edat[p] = ((u64)__float_as_uint(w) << 32) | (unsigned)s;
}

// ---------------- deg from placed rows: deg[i] = 1 + sum of row ew (no atomics) ----------------
__global__ __launch_bounds__(256) void k_deg(const int* __restrict__ rowptr, const int* __restrict__ cnt,
                                             const u64* __restrict__ edat, float* __restrict__ deg, int N) {
    int i = blockIdx.x * 256 + threadIdx.x;
    if (i >= N) return;
    int rp = rowptr[i], c = cnt[i];
    float s = 1.0f;   // self loop
    for (int j = 0; j < c; ++j)
        s += __uint_as_float((unsigned)(edat[rp + j] >> 32));
    deg[i] = s;
}

// ---------------- Y[n][j] = half( rsqrt(deg[n]) * sum_k X[n][k] * W[j][k] ) ----------------
__global__ __launch_bounds__(256) void k_gemm64h(
    const float* __restrict__ X, const float* __restrict__ W, const float* __restrict__ deg,
    __half* __restrict__ Y, int n)
{
    __shared__ float w[64][64];
    for (int i = threadIdx.x; i < 64 * 64; i += 256) w[i >> 6][i & 63] = W[i];
    __syncthreads();
    int node = blockIdx.x * 256 + threadIdx.x;
    if (node >= n) return;
    float r[64];
    const float4* xr = (const float4*)(X + (size_t)node * 64);
#pragma unroll
    for (int q = 0; q < 16; ++q) {
        float4 v = xr[q];
        r[4 * q] = v.x; r[4 * q + 1] = v.y; r[4 * q + 2] = v.z; r[4 * q + 3] = v.w;
    }
    float ds = rsqrtf(deg[node]);
    uint2* yr = (uint2*)(Y + (size_t)node * 64);
    for (int j = 0; j < 64; j += 4) {
        float a0 = 0.f, a1 = 0.f, a2 = 0.f, a3 = 0.f;
#pragma unroll
        for (int k = 0; k < 64; ++k) {
            a0 += r[k] * w[j][k];
            a1 += r[k] * w[j + 1][k];
            a2 += r[k] * w[j + 2][k];
            a3 += r[k] * w[j + 3][k];
        }
        __half2 h01 = __floats2half2_rn(ds * a0, ds * a1);
        __half2 h23 = __floats2half2_rn(ds * a2, ds * a3);
        uint2 pk;
        pk.x = *(unsigned*)&h01;
        pk.y = *(unsigned*)&h23;
        yr[j >> 2] = pk;
    }
}

// ---------------- gather-aggregate: 2 edges/iter-pair via half2 lanes ----------------
__device__ __forceinline__ float2 agg_node2(const __half2* __restrict__ A2, const u64* __restrict__ ed,
                                            int c, int lane)
{
    int g = lane >> 5;
    int l = lane & 31;
    float2 acc = {0.f, 0.f};
    int cm1 = (c > 0) ? c - 1 : 0;
    for (int jb = 0; jb < c; jb += 16) {
        u64 myrec = ed[min(jb + (lane & 15), cm1)];   // 16 records, coalesced
        u64 rec[8];
#pragma unroll
        for (int q = 0; q < 8; ++q) rec[q] = __shfl(myrec, 2 * q + g);
        unsigned raw[8];
#pragma unroll
        for (int q = 0; q < 8; ++q) {
            int s = (int)(unsigned)(rec[q] & 0xffffffffu);
            raw[q] = *(const unsigned*)&A2[(size_t)s * 32 + l];   // 8 gathers in flight
        }
#pragma unroll
        for (int q = 0; q < 8; ++q) {
            int idx = jb + 2 * q + g;
            float w = (idx < c) ? __uint_as_float((unsigned)(rec[q] >> 32)) : 0.f;
            __half2 hv = *(__half2*)&raw[q];
            float2 v = __half22float2(hv);
            acc.x += w * v.x;
            acc.y += w * v.y;
        }
    }
    acc.x += __shfl_xor(acc.x, 32);
    acc.y += __shfl_xor(acc.y, 32);
    return acc;
}

// ---------------- layer-1 aggregate + self-loop + bias + ReLU ----------------
__global__ __launch_bounds__(256) void k_agg1(
    const __half* __restrict__ A, const int* __restrict__ rowptr, const int* __restrict__ cnt,
    const u64* __restrict__ edat, const float* __restrict__ deg,
    const float* __restrict__ b1, float* __restrict__ H, int N)
{
    int node = blockIdx.x * 4 + (threadIdx.x >> 6);
    if (node >= N) return;
    int lane = threadIdx.x & 63;
    int l = lane & 31;
    const __half2* A2 = (const __half2*)A;
    float2 acc = agg_node2(A2, edat + rowptr[node], cnt[node], lane);
    float dsd = rsqrtf(deg[node]);
    float2 self = __half22float2(A2[(size_t)node * 32 + l]);
    float2 bb = ((const float2*)b1)[l];
    if (lane < 32) {
        float2 h;
        h.x = fmaxf(dsd * (acc.x + self.x) + bb.x, 0.f);
        h.y = fmaxf(dsd * (acc.y + self.y) + bb.y, 0.f);
        ((float2*)(H + (size_t)node * 64))[l] = h;
    }
}

// ---------------- layer-2 aggregate fused with classifier + softmax ----------------
__global__ __launch_bounds__(256) void k_agg2_final(
    const __half* __restrict__ A, const int* __restrict__ rowptr, const int* __restrict__ cnt,
    const u64* __restrict__ edat, const float* __restrict__ deg,
    const float* __restrict__ b2, const float* __restrict__ labels,
    const float* __restrict__ Wc, const float* __restrict__ bc,
    float* __restrict__ out, int N)
{
    int node = blockIdx.x * 4 + (threadIdx.x >> 6);
    if (node >= N) return;
    int lane = threadIdx.x & 63;
    int l = lane & 31;
    const __half2* A2 = (const __half2*)A;
    float2 acc = agg_node2(A2, edat + rowptr[node], cnt[node], lane);
    float dsd = rsqrtf(deg[node]);
    float2 self = __half22float2(A2[(size_t)node * 32 + l]);
    float2 bb = ((const float2*)b2)[l];
    float hx = dsd * (acc.x + self.x) + bb.x;
    float hy = dsd * (acc.y + self.y) + bb.y;
    float2 wc0 = ((const float2*)Wc)[l];
    float w1x = Wc[65 + 2 * l], w1y = Wc[65 + 2 * l + 1];
    float p0 = hx * wc0.x + hy * wc0.y;
    float p1 = hx * w1x + hy * w1y;
    if (lane >= 32) { p0 = 0.f; p1 = 0.f; }   // halves are duplicated post-combine
#pragma unroll
    for (int mm = 1; mm < 64; mm <<= 1) {
        p0 += __shfl_xor(p0, mm);
        p1 += __shfl_xor(p1, mm);
    }
    if (lane == 0) {
        float lab = labels[node];
        float l0 = p0 + lab * Wc[64] + bc[0];
        float l1 = p1 + lab * Wc[65 + 64] + bc[1];
        float mx = fmaxf(l0, l1);
        float e0 = expf(l0 - mx), e1 = expf(l1 - mx);
        float inv = 1.0f / (e0 + e1);
        out[2 * (size_t)node]     = e0 * inv;
        out[2 * (size_t)node + 1] = e1 * inv;
    }
}

extern "C" void kernel_launch(void* const* d_in, const int* in_sizes, int n_in,
                              void* d_out, int out_size, void* d_ws, size_t ws_size,
                              hipStream_t stream)
{
    const float* emb      = (const float*)d_in[0];
    const float* features = (const float*)d_in[1];
    const float* labels   = (const float*)d_in[2];
    const float* Wv       = (const float*)d_in[3];
    const float* bv       = (const float*)d_in[4];
    const float* W1       = (const float*)d_in[5];
    const float* b1       = (const float*)d_in[6];
    const float* W2       = (const float*)d_in[7];
    const float* b2       = (const float*)d_in[8];
    const float* Wc       = (const float*)d_in[9];
    const float* bc       = (const float*)d_in[10];
    const int*   eidx     = (const int*)d_in[11];

    const int E = in_sizes[11] / 2;   // 1600000
    const int N = in_sizes[1] / 64;   // 100000
    const int* src = eidx;
    const int* dst = eidx + E;

    float* out      = (float*)d_out;
    float* out_sens = out;                  // N*2
    float* out_ew   = out + 2 * (size_t)N;  // E

    // workspace layout (4B units):
    // deg[N] | Ah[N*64 halves] | H[N*64] | cnt[N] | rowptr[N] | cursor[N] | bsum[128] | boff[128] | edat[E u64]
    float*  deg    = (float*)d_ws;
    __half* Ah     = (__half*)(deg + N);
    float*  H      = (float*)(Ah + (size_t)N * 64);
    int*    cnt    = (int*)(H + (size_t)N * 64);
    int*    rowptr = cnt + N;
    int*    cursor = rowptr + N;
    int*    bsum   = cursor + N;
    int*    boff   = bsum + 128;
    u64*    edat   = (u64*)(boff + 128);

    const int NB = (N + 1023) / 1024;   // 98 <= 128

    // CSR skeleton (independent of ew)
    k_init<<<(N + 255) / 256, 256, 0, stream>>>(cnt, N);
    k_cnt<<<(E + 255) / 256, 256, 0, stream>>>(dst, cnt, E);
    k_scan_bsum<<<NB, 256, 0, stream>>>(cnt, bsum, N);
    k_scan_top<<<1, 128, 0, stream>>>(bsum, boff, NB);
    k_scan_write<<<NB, 256, 0, stream>>>(cnt, boff, rowptr, cursor, N);

    // pure streaming pass
    k_edge_ew<<<(E / 4 + 7) / 8, 256, 0, stream>>>(emb, Wv, bv, out_ew, E);

    // placement + deg from rows
    k_place<<<(E + 255) / 256, 256, 0, stream>>>(src, dst, out_ew, cursor, edat, E);
    k_deg<<<(N + 255) / 256, 256, 0, stream>>>(rowptr, cnt, edat, deg, N);

    // layer 1
    k_gemm64h<<<(N + 255) / 256, 256, 0, stream>>>(features, W1, deg, Ah, N);
    k_agg1<<<(N + 3) / 4, 256, 0, stream>>>(Ah, rowptr, cnt, edat, deg, b1, H, N);

    // layer 2 + classifier + softmax
    k_gemm64h<<<(N + 255) / 256, 256, 0, stream>>>(H, W2, deg, Ah, N);
    k_agg2_final<<<(N + 3) / 4, 256, 0, stream>>>(Ah, rowptr, cnt, edat, deg, b2,
                                                  labels, Wc, bc, out_sens, N);
}

// Round 8
// 438.767 us; speedup vs baseline: 1.4565x; 1.2423x over previous
//
#include <hip/hip_runtime.h>
#include <hip/hip_bf16.h>
#include <hip/hip_fp16.h>
#include <math.h>

typedef unsigned long long u64;

#define SHIFT 10
#define BSZ   1024            // nodes per bucket
#define MAXBK 128             // >= nbk
#define EPB   4096            // edges per partition block

// ---------------- edge weight: PURE STREAM: out_ew = 1 - sigmoid(emb@Wv+bv) ----------------
__global__ __launch_bounds__(256) void k_edge_ew(
    const float* __restrict__ emb, const float* __restrict__ Wv, const float* __restrict__ bv,
    float* __restrict__ out_ew, int E)
{
    int grp = blockIdx.x * 8 + (threadIdx.x >> 5);
    int base = grp * 4;
    if (base >= E) return;
    int l = threadIdx.x & 31;
    const float4* embp = (const float4*)emb;
    const float4 w = ((const float4*)Wv)[l];
    float dot[4];
#pragma unroll
    for (int q = 0; q < 4; ++q) {
        const float4 v = embp[(size_t)(base + q) * 32 + l];   // E % 4 == 0
        dot[q] = v.x * w.x + v.y * w.y + v.z * w.z + v.w * w.w;
    }
#pragma unroll
    for (int m = 16; m >= 1; m >>= 1) {
#pragma unroll
        for (int q = 0; q < 4; ++q) dot[q] += __shfl_xor(dot[q], m);
    }
    if (l == 0) {
        float bv0 = bv[0];
        float s[4];
#pragma unroll
        for (int q = 0; q < 4; ++q) s[q] = 1.0f / (1.0f + expf(-(dot[q] + bv0)));
        float4 o = {1.0f - s[0], 1.0f - s[1], 1.0f - s[2], 1.0f - s[3]};
        ((float4*)out_ew)[grp] = o;
    }
}

// ---------------- P1: per-(block,bucket) histogram, LDS atomics only ----------------
__global__ __launch_bounds__(256) void k_hist(const int* __restrict__ dst, int* __restrict__ ghist,
                                              int E, int nbk, int nblk)
{
    __shared__ int h[MAXBK];
    int t = threadIdx.x, b = blockIdx.x;
    if (t < nbk) h[t] = 0;
    __syncthreads();
    int base = b * EPB, end = min(base + EPB, E);
    for (int i = base + t; i < end; i += 256) atomicAdd(&h[dst[i] >> SHIFT], 1);
    __syncthreads();
    if (t < nbk) ghist[t * nblk + b] = h[t];
}

// ---------------- P2a: per-bucket column scan (one block per bucket) ----------------
__global__ __launch_bounds__(512) void k_scan_col(int* __restrict__ ghist, int* __restrict__ btot, int nblk)
{
    __shared__ int sA[512], sB[512];
    int k = blockIdx.x, t = threadIdx.x;
    int v = (t < nblk) ? ghist[k * nblk + t] : 0;
    sA[t] = v; __syncthreads();
    int* cur = sA; int* nxt = sB;
    for (int off = 1; off < 512; off <<= 1) {
        int x = cur[t];
        if (t >= off) x += cur[t - off];
        nxt[t] = x; __syncthreads();
        int* tmp = cur; cur = nxt; nxt = tmp;
    }
    if (t < nblk) ghist[k * nblk + t] = cur[t] - v;   // exclusive within bucket
    if (t == 511) btot[k] = cur[511];                 // bucket total
}

// ---------------- P2b: exclusive scan of bucket totals ----------------
__global__ void k_scan_tot(const int* __restrict__ btot, int* __restrict__ bstart, int nbk)
{
    if (threadIdx.x == 0 && blockIdx.x == 0) {
        int run = 0;
        for (int k = 0; k < nbk; ++k) { bstart[k] = run; run += btot[k]; }
        bstart[nbk] = run;
    }
}

// ---------------- P3: bin records into LDS, flush bucket chunks coalesced ----------------
// tmp record: [ew:32 | dlocal:10 (bits 17..26) | src:17]
__global__ __launch_bounds__(256) void k_scatter(
    const int* __restrict__ src, const int* __restrict__ dst, const float* __restrict__ out_ew,
    const int* __restrict__ ghist, const int* __restrict__ bstart,
    u64* __restrict__ tmp, int E, int nbk, int nblk)
{
    __shared__ int lofs[MAXBK + 1];
    __shared__ int lcur[MAXBK];
    __shared__ u64 recs[EPB];   // 32 KB
    int t = threadIdx.x, b = blockIdx.x;
    if (t < nbk) lcur[t] = 0;
    __syncthreads();
    int base = b * EPB, end = min(base + EPB, E);
    for (int i = base + t; i < end; i += 256) atomicAdd(&lcur[dst[i] >> SHIFT], 1);
    __syncthreads();
    if (t == 0) {
        int run = 0;
        for (int k = 0; k < nbk; ++k) { lofs[k] = run; run += lcur[k]; }
        lofs[nbk] = run;
    }
    __syncthreads();
    if (t < nbk) lcur[t] = lofs[t];
    __syncthreads();
    for (int i = base + t; i < end; i += 256) {
        int d = dst[i];
        int k = d >> SHIFT;
        int p = atomicAdd(&lcur[k], 1);
        float w = 1.0f - out_ew[i];
        recs[p] = ((u64)__float_as_uint(w) << 32) | ((u64)(unsigned)(d & (BSZ - 1)) << 17)
                | (u64)(unsigned)src[i];
    }
    __syncthreads();
    for (int k = 0; k < nbk; ++k) {
        int s0 = lofs[k];
        int ck = lofs[k + 1] - s0;
        int gbase = bstart[k] + ghist[k * nblk + b];
        for (int j = t; j < ck; j += 256) tmp[gbase + j] = recs[s0 + j];
    }
}

// ---------------- P4: per-bucket CSR build: rowptr/cnt/deg + final edat, all LDS-local ----------------
__global__ __launch_bounds__(512) void k_build(
    const u64* __restrict__ tmp, const int* __restrict__ bstart,
    u64* __restrict__ edat, int* __restrict__ rowptr, int* __restrict__ cnt,
    float* __restrict__ deg, int N)
{
    __shared__ int   lcnt[BSZ];
    __shared__ int   lcur[BSZ];
    __shared__ float ldeg[BSZ];
    __shared__ int   sA[512], sB[512];
    int k = blockIdx.x, t = threadIdx.x;
    int nodeBase = k * BSZ;
    int r0 = bstart[k], r1 = bstart[k + 1];
    for (int i = t; i < BSZ; i += 512) { lcnt[i] = 0; ldeg[i] = 1.0f; }  // self loop
    __syncthreads();
    for (int i = r0 + t; i < r1; i += 512) {
        u64 rec = tmp[i];
        int dl = (int)((rec >> 17) & (BSZ - 1));
        atomicAdd(&lcnt[dl], 1);
        atomicAdd(&ldeg[dl], __uint_as_float((unsigned)(rec >> 32)));
    }
    __syncthreads();
    // exclusive scan of lcnt[1024] with 512 threads
    int a = lcnt[2 * t], bb = lcnt[2 * t + 1];
    sA[t] = a + bb; __syncthreads();
    int* cur = sA; int* nxt = sB;
    for (int off = 1; off < 512; off <<= 1) {
        int x = cur[t];
        if (t >= off) x += cur[t - off];
        nxt[t] = x; __syncthreads();
        int* tp = cur; cur = nxt; nxt = tp;
    }
    int excl = cur[t] - (a + bb);
    lcur[2 * t] = excl;
    lcur[2 * t + 1] = excl + a;
    __syncthreads();
    for (int i = t; i < BSZ; i += 512) {
        int node = nodeBase + i;
        if (node < N) {
            rowptr[node] = r0 + lcur[i];
            cnt[node]    = lcnt[i];
            deg[node]    = ldeg[i];
        }
    }
    __syncthreads();
    for (int i = r0 + t; i < r1; i += 512) {
        u64 rec = tmp[i];
        int dl = (int)((rec >> 17) & (BSZ - 1));
        int p = atomicAdd(&lcur[dl], 1);
        edat[r0 + p] = ((rec >> 32) << 32) | (rec & 0x1FFFFull);
    }
}

// ---------------- Y[n][j] = half( rsqrt(deg[n]) * sum_k X[n][k] * W[j][k] ) ----------------
__global__ __launch_bounds__(256) void k_gemm64h(
    const float* __restrict__ X, const float* __restrict__ W, const float* __restrict__ deg,
    __half* __restrict__ Y, int n)
{
    __shared__ float w[64][64];
    for (int i = threadIdx.x; i < 64 * 64; i += 256) w[i >> 6][i & 63] = W[i];
    __syncthreads();
    int node = blockIdx.x * 256 + threadIdx.x;
    if (node >= n) return;
    float r[64];
    const float4* xr = (const float4*)(X + (size_t)node * 64);
#pragma unroll
    for (int q = 0; q < 16; ++q) {
        float4 v = xr[q];
        r[4 * q] = v.x; r[4 * q + 1] = v.y; r[4 * q + 2] = v.z; r[4 * q + 3] = v.w;
    }
    float ds = rsqrtf(deg[node]);
    uint2* yr = (uint2*)(Y + (size_t)node * 64);
    for (int j = 0; j < 64; j += 4) {
        float a0 = 0.f, a1 = 0.f, a2 = 0.f, a3 = 0.f;
#pragma unroll
        for (int kk = 0; kk < 64; ++kk) {
            a0 += r[kk] * w[j][kk];
            a1 += r[kk] * w[j + 1][kk];
            a2 += r[kk] * w[j + 2][kk];
            a3 += r[kk] * w[j + 3][kk];
        }
        __half2 h01 = __floats2half2_rn(ds * a0, ds * a1);
        __half2 h23 = __floats2half2_rn(ds * a2, ds * a3);
        uint2 pk;
        pk.x = *(unsigned*)&h01;
        pk.y = *(unsigned*)&h23;
        yr[j >> 2] = pk;
    }
}

// ---------------- gather-aggregate: 2 edges/iter-pair via half2 lanes ----------------
__device__ __forceinline__ float2 agg_node2(const __half2* __restrict__ A2, const u64* __restrict__ ed,
                                            int c, int lane)
{
    int g = lane >> 5;
    int l = lane & 31;
    float2 acc = {0.f, 0.f};
    int cm1 = (c > 0) ? c - 1 : 0;
    for (int jb = 0; jb < c; jb += 16) {
        u64 myrec = ed[min(jb + (lane & 15), cm1)];   // 16 records, coalesced
        u64 rec[8];
#pragma unroll
        for (int q = 0; q < 8; ++q) rec[q] = __shfl(myrec, 2 * q + g);
        unsigned raw[8];
#pragma unroll
        for (int q = 0; q < 8; ++q) {
            int s = (int)(unsigned)(rec[q] & 0xffffffffu);
            raw[q] = *(const unsigned*)&A2[(size_t)s * 32 + l];   // 8 gathers in flight
        }
#pragma unroll
        for (int q = 0; q < 8; ++q) {
            int idx = jb + 2 * q + g;
            float w = (idx < c) ? __uint_as_float((unsigned)(rec[q] >> 32)) : 0.f;
            __half2 hv = *(__half2*)&raw[q];
            float2 v = __half22float2(hv);
            acc.x += w * v.x;
            acc.y += w * v.y;
        }
    }
    acc.x += __shfl_xor(acc.x, 32);
    acc.y += __shfl_xor(acc.y, 32);
    return acc;
}

// ---------------- layer-1 aggregate + self-loop + bias + ReLU ----------------
__global__ __launch_bounds__(256) void k_agg1(
    const __half* __restrict__ A, const int* __restrict__ rowptr, const int* __restrict__ cnt,
    const u64* __restrict__ edat, const float* __restrict__ deg,
    const float* __restrict__ b1, float* __restrict__ H, int N)
{
    int node = blockIdx.x * 4 + (threadIdx.x >> 6);
    if (node >= N) return;
    int lane = threadIdx.x & 63;
    int l = lane & 31;
    const __half2* A2 = (const __half2*)A;
    float2 acc = agg_node2(A2, edat + rowptr[node], cnt[node], lane);
    float dsd = rsqrtf(deg[node]);
    float2 self = __half22float2(A2[(size_t)node * 32 + l]);
    float2 bb = ((const float2*)b1)[l];
    if (lane < 32) {
        float2 h;
        h.x = fmaxf(dsd * (acc.x + self.x) + bb.x, 0.f);
        h.y = fmaxf(dsd * (acc.y + self.y) + bb.y, 0.f);
        ((float2*)(H + (size_t)node * 64))[l] = h;
    }
}

// ---------------- layer-2 aggregate fused with classifier + softmax ----------------
__global__ __launch_bounds__(256) void k_agg2_final(
    const __half* __restrict__ A, const int* __restrict__ rowptr, const int* __restrict__ cnt,
    const u64* __restrict__ edat, const float* __restrict__ deg,
    const float* __restrict__ b2, const float* __restrict__ labels,
    const float* __restrict__ Wc, const float* __restrict__ bc,
    float* __restrict__ out, int N)
{
    int node = blockIdx.x * 4 + (threadIdx.x >> 6);
    if (node >= N) return;
    int lane = threadIdx.x & 63;
    int l = lane & 31;
    const __half2* A2 = (const __half2*)A;
    float2 acc = agg_node2(A2, edat + rowptr[node], cnt[node], lane);
    float dsd = rsqrtf(deg[node]);
    float2 self = __half22float2(A2[(size_t)node * 32 + l]);
    float2 bb = ((const float2*)b2)[l];
    float hx = dsd * (acc.x + self.x) + bb.x;
    float hy = dsd * (acc.y + self.y) + bb.y;
    float2 wc0 = ((const float2*)Wc)[l];
    float w1x = Wc[65 + 2 * l], w1y = Wc[65 + 2 * l + 1];
    float p0 = hx * wc0.x + hy * wc0.y;
    float p1 = hx * w1x + hy * w1y;
    if (lane >= 32) { p0 = 0.f; p1 = 0.f; }   // halves duplicated post-combine
#pragma unroll
    for (int mm = 1; mm < 64; mm <<= 1) {
        p0 += __shfl_xor(p0, mm);
        p1 += __shfl_xor(p1, mm);
    }
    if (lane == 0) {
        float lab = labels[node];
        float l0 = p0 + lab * Wc[64] + bc[0];
        float l1 = p1 + lab * Wc[65 + 64] + bc[1];
        float mx = fmaxf(l0, l1);
        float e0 = expf(l0 - mx), e1 = expf(l1 - mx);
        float inv = 1.0f / (e0 + e1);
        out[2 * (size_t)node]     = e0 * inv;
        out[2 * (size_t)node + 1] = e1 * inv;
    }
}

extern "C" void kernel_launch(void* const* d_in, const int* in_sizes, int n_in,
                              void* d_out, int out_size, void* d_ws, size_t ws_size,
                              hipStream_t stream)
{
    const float* emb      = (const float*)d_in[0];
    const float* features = (const float*)d_in[1];
    const float* labels   = (const float*)d_in[2];
    const float* Wv       = (const float*)d_in[3];
    const float* bv       = (const float*)d_in[4];
    const float* W1       = (const float*)d_in[5];
    const float* b1       = (const float*)d_in[6];
    const float* W2       = (const float*)d_in[7];
    const float* b2       = (const float*)d_in[8];
    const float* Wc       = (const float*)d_in[9];
    const float* bc       = (const float*)d_in[10];
    const int*   eidx     = (const int*)d_in[11];

    const int E = in_sizes[11] / 2;   // 1600000
    const int N = in_sizes[1] / 64;   // 100000
    const int* src = eidx;
    const int* dst = eidx + E;

    float* out      = (float*)d_out;
    float* out_sens = out;                  // N*2
    float* out_ew   = out + 2 * (size_t)N;  // E

    const int nbk  = (N + BSZ - 1) >> SHIFT;       // 98
    const int nblk = (E + EPB - 1) / EPB;          // 391

    // workspace layout (4B units, keep u64 regions 8B aligned):
    // deg[N] | Ah[N*32 u32] | H[N*64] | cnt[N] | rowptr[N] | ghist[nbk*nblk] | btot[nbk]
    // | bstart[nbk+1 padded even] | tmp[E u64] | edat[E u64]
    float*  deg    = (float*)d_ws;
    __half* Ah     = (__half*)(deg + N);
    float*  H      = (float*)(Ah + (size_t)N * 64);
    int*    cnt    = (int*)(H + (size_t)N * 64);
    int*    rowptr = cnt + N;
    int*    ghist  = rowptr + N;
    int*    btot   = ghist + (size_t)nbk * nblk;
    int*    bstart = btot + nbk;
    int*    endi   = bstart + ((nbk + 2) & ~1);    // even padding
    u64*    tmp    = (u64*)((((size_t)(endi - (int*)d_ws)) + 1 & ~(size_t)1) * 4 + (char*)d_ws);
    u64*    edat   = tmp + E;

    // pure streaming pass (independent; launch first)
    k_edge_ew<<<(E / 4 + 7) / 8, 256, 0, stream>>>(emb, Wv, bv, out_ew, E);

    // radix CSR build — zero random global atomics
    k_hist<<<nblk, 256, 0, stream>>>(dst, ghist, E, nbk, nblk);
    k_scan_col<<<nbk, 512, 0, stream>>>(ghist, btot, nblk);
    k_scan_tot<<<1, 64, 0, stream>>>(btot, bstart, nbk);
    k_scatter<<<nblk, 256, 0, stream>>>(src, dst, out_ew, ghist, bstart, tmp, E, nbk, nblk);
    k_build<<<nbk, 512, 0, stream>>>(tmp, bstart, edat, rowptr, cnt, deg, N);

    // layer 1
    k_gemm64h<<<(N + 255) / 256, 256, 0, stream>>>(features, W1, deg, Ah, N);
    k_agg1<<<(N + 3) / 4, 256, 0, stream>>>(Ah, rowptr, cnt, edat, deg, b1, H, N);

    // layer 2 + classifier + softmax
    k_gemm64h<<<(N + 255) / 256, 256, 0, stream>>>(H, W2, deg, Ah, N);
    k_agg2_final<<<(N + 3) / 4, 256, 0, stream>>>(Ah, rowptr, cnt, edat, deg, b2,
                                                  labels, Wc, bc, out_sens, N);
}

// Round 9
// 418.741 us; speedup vs baseline: 1.5261x; 1.0478x over previous
//
#include <hip/hip_runtime.h>
#include <hip/hip_bf16.h>
#include <hip/hip_fp16.h>
#include <math.h>

typedef unsigned long long u64;

#define SHIFT 10
#define BSZ   1024            // nodes per bucket
#define MAXBK 128             // >= nbk
#define EPB   4096            // edges per partition block

// ---------------- edge weight: PURE STREAM: out_ew = 1 - sigmoid(emb@Wv+bv) ----------------
__global__ __launch_bounds__(256) void k_edge_ew(
    const float* __restrict__ emb, const float* __restrict__ Wv, const float* __restrict__ bv,
    float* __restrict__ out_ew, int E)
{
    int grp = blockIdx.x * 8 + (threadIdx.x >> 5);
    int base = grp * 4;
    if (base >= E) return;
    int l = threadIdx.x & 31;
    const float4* embp = (const float4*)emb;
    const float4 w = ((const float4*)Wv)[l];
    float dot[4];
#pragma unroll
    for (int q = 0; q < 4; ++q) {
        const float4 v = embp[(size_t)(base + q) * 32 + l];   // E % 4 == 0
        dot[q] = v.x * w.x + v.y * w.y + v.z * w.z + v.w * w.w;
    }
#pragma unroll
    for (int m = 16; m >= 1; m >>= 1) {
#pragma unroll
        for (int q = 0; q < 4; ++q) dot[q] += __shfl_xor(dot[q], m);
    }
    if (l == 0) {
        float bv0 = bv[0];
        float s[4];
#pragma unroll
        for (int q = 0; q < 4; ++q) s[q] = 1.0f / (1.0f + expf(-(dot[q] + bv0)));
        float4 o = {1.0f - s[0], 1.0f - s[1], 1.0f - s[2], 1.0f - s[3]};
        ((float4*)out_ew)[grp] = o;
    }
}

// ---------------- P1: per-(block,bucket) histogram, LDS atomics only ----------------
__global__ __launch_bounds__(256) void k_hist(const int* __restrict__ dst, int* __restrict__ ghist,
                                              int E, int nbk, int nblk)
{
    __shared__ int h[MAXBK];
    int t = threadIdx.x, b = blockIdx.x;
    if (t < nbk) h[t] = 0;
    __syncthreads();
    int base = b * EPB, end = min(base + EPB, E);
    for (int i = base + t; i < end; i += 256) atomicAdd(&h[dst[i] >> SHIFT], 1);
    __syncthreads();
    if (t < nbk) ghist[t * nblk + b] = h[t];
}

// ---------------- P2a: per-bucket column scan (one block per bucket) ----------------
__global__ __launch_bounds__(512) void k_scan_col(int* __restrict__ ghist, int* __restrict__ btot, int nblk)
{
    __shared__ int sA[512], sB[512];
    int k = blockIdx.x, t = threadIdx.x;
    int v = (t < nblk) ? ghist[k * nblk + t] : 0;
    sA[t] = v; __syncthreads();
    int* cur = sA; int* nxt = sB;
    for (int off = 1; off < 512; off <<= 1) {
        int x = cur[t];
        if (t >= off) x += cur[t - off];
        nxt[t] = x; __syncthreads();
        int* tmp = cur; cur = nxt; nxt = tmp;
    }
    if (t < nblk) ghist[k * nblk + t] = cur[t] - v;   // exclusive within bucket
    if (t == 511) btot[k] = cur[511];                 // bucket total
}

// ---------------- P2b: exclusive scan of bucket totals ----------------
__global__ void k_scan_tot(const int* __restrict__ btot, int* __restrict__ bstart, int nbk)
{
    if (threadIdx.x == 0 && blockIdx.x == 0) {
        int run = 0;
        for (int k = 0; k < nbk; ++k) { bstart[k] = run; run += btot[k]; }
        bstart[nbk] = run;
    }
}

// ---------------- P3: bin records into LDS, flush FULLY PARALLEL (binary search) ----------------
// tmp record: [ew:32 | dlocal:10 (bits 17..26) | src:17]
__global__ __launch_bounds__(256) void k_scatter(
    const int* __restrict__ src, const int* __restrict__ dst, const float* __restrict__ out_ew,
    const int* __restrict__ ghist, const int* __restrict__ bstart,
    u64* __restrict__ tmp, int E, int nbk, int nblk)
{
    __shared__ int lofs[MAXBK + 1];
    __shared__ int lcur[MAXBK];
    __shared__ int gdst[MAXBK];
    __shared__ u64 recs[EPB];   // 32 KB
    int t = threadIdx.x, b = blockIdx.x;
    if (t < nbk) lcur[t] = 0;
    __syncthreads();
    int base = b * EPB, end = min(base + EPB, E);
    for (int i = base + t; i < end; i += 256) atomicAdd(&lcur[dst[i] >> SHIFT], 1);
    __syncthreads();
    if (t == 0) {
        int run = 0;
        for (int k = 0; k < nbk; ++k) { lofs[k] = run; run += lcur[k]; }
        lofs[nbk] = run;
    }
    __syncthreads();
    if (t < nbk) {
        lcur[t] = lofs[t];
        gdst[t] = bstart[t] + ghist[t * nblk + b];   // all dest bases in one parallel shot
    }
    __syncthreads();
    for (int i = base + t; i < end; i += 256) {
        int d = dst[i];
        int k = d >> SHIFT;
        int p = atomicAdd(&lcur[k], 1);
        float w = 1.0f - out_ew[i];
        recs[p] = ((u64)__float_as_uint(w) << 32) | ((u64)(unsigned)(d & (BSZ - 1)) << 17)
                | (u64)(unsigned)src[i];
    }
    __syncthreads();
    int total = end - base;
    for (int j = t; j < total; j += 256) {
        int lo = 0, hi = nbk;               // find lo: lofs[lo] <= j < lofs[lo+1]
        while (hi - lo > 1) {
            int mid = (lo + hi) >> 1;
            if (lofs[mid] <= j) lo = mid; else hi = mid;
        }
        tmp[gdst[lo] + (j - lofs[lo])] = recs[j];
    }
}

// ---------------- P4: per-bucket CSR build: rowptr/cnt/deg + final edat, all LDS-local ----------------
__global__ __launch_bounds__(512) void k_build(
    const u64* __restrict__ tmp, const int* __restrict__ bstart,
    u64* __restrict__ edat, int* __restrict__ rowptr, int* __restrict__ cnt,
    float* __restrict__ deg, int N)
{
    __shared__ int   lcnt[BSZ];
    __shared__ int   lcur[BSZ];
    __shared__ float ldeg[BSZ];
    __shared__ int   sA[512], sB[512];
    int k = blockIdx.x, t = threadIdx.x;
    int nodeBase = k * BSZ;
    int r0 = bstart[k], r1 = bstart[k + 1];
    for (int i = t; i < BSZ; i += 512) { lcnt[i] = 0; ldeg[i] = 1.0f; }  // self loop
    __syncthreads();
    for (int i = r0 + t; i < r1; i += 512) {
        u64 rec = tmp[i];
        int dl = (int)((rec >> 17) & (BSZ - 1));
        atomicAdd(&lcnt[dl], 1);
        atomicAdd(&ldeg[dl], __uint_as_float((unsigned)(rec >> 32)));
    }
    __syncthreads();
    int a = lcnt[2 * t], bb = lcnt[2 * t + 1];
    sA[t] = a + bb; __syncthreads();
    int* cur = sA; int* nxt = sB;
    for (int off = 1; off < 512; off <<= 1) {
        int x = cur[t];
        if (t >= off) x += cur[t - off];
        nxt[t] = x; __syncthreads();
        int* tp = cur; cur = nxt; nxt = tp;
    }
    int excl = cur[t] - (a + bb);
    lcur[2 * t] = excl;
    lcur[2 * t + 1] = excl + a;
    __syncthreads();
    for (int i = t; i < BSZ; i += 512) {
        int node = nodeBase + i;
        if (node < N) {
            rowptr[node] = r0 + lcur[i];
            cnt[node]    = lcnt[i];
            deg[node]    = ldeg[i];
        }
    }
    __syncthreads();
    for (int i = r0 + t; i < r1; i += 512) {
        u64 rec = tmp[i];
        int dl = (int)((rec >> 17) & (BSZ - 1));
        int p = atomicAdd(&lcur[dl], 1);
        edat[r0 + p] = ((rec >> 32) << 32) | (rec & 0x1FFFFull);
    }
}

// ---------------- Y[n][j] = half( rsqrt(deg[n]) * sum_k X[n][k] * W[j][k] ) ----------------
__global__ __launch_bounds__(256) void k_gemm64h(
    const float* __restrict__ X, const float* __restrict__ W, const float* __restrict__ deg,
    __half* __restrict__ Y, int n)
{
    __shared__ float w[64][64];
    for (int i = threadIdx.x; i < 64 * 64; i += 256) w[i >> 6][i & 63] = W[i];
    __syncthreads();
    int node = blockIdx.x * 256 + threadIdx.x;
    if (node >= n) return;
    float r[64];
    const float4* xr = (const float4*)(X + (size_t)node * 64);
#pragma unroll
    for (int q = 0; q < 16; ++q) {
        float4 v = xr[q];
        r[4 * q] = v.x; r[4 * q + 1] = v.y; r[4 * q + 2] = v.z; r[4 * q + 3] = v.w;
    }
    float ds = rsqrtf(deg[node]);
    uint2* yr = (uint2*)(Y + (size_t)node * 64);
    for (int j = 0; j < 64; j += 4) {
        float a0 = 0.f, a1 = 0.f, a2 = 0.f, a3 = 0.f;
#pragma unroll
        for (int kk = 0; kk < 64; ++kk) {
            a0 += r[kk] * w[j][kk];
            a1 += r[kk] * w[j + 1][kk];
            a2 += r[kk] * w[j + 2][kk];
            a3 += r[kk] * w[j + 3][kk];
        }
        __half2 h01 = __floats2half2_rn(ds * a0, ds * a1);
        __half2 h23 = __floats2half2_rn(ds * a2, ds * a3);
        uint2 pk;
        pk.x = *(unsigned*)&h01;
        pk.y = *(unsigned*)&h23;
        yr[j >> 2] = pk;
    }
}

// ---------------- gather-aggregate: peeled main loop (no clamp) + clamped tail ----------------
__device__ __forceinline__ float2 agg_node2(const __half2* __restrict__ A2, const u64* __restrict__ ed,
                                            int c, int lane)
{
    int g = lane >> 5;
    int l = lane & 31;
    float2 acc = {0.f, 0.f};
    int jb = 0;
    for (; jb + 16 <= c; jb += 16) {                  // full blocks: no clamps, no masks
        u64 myrec = ed[jb + (lane & 15)];
        u64 rec[8];
#pragma unroll
        for (int q = 0; q < 8; ++q) rec[q] = __shfl(myrec, 2 * q + g);
        unsigned raw[8];
#pragma unroll
        for (int q = 0; q < 8; ++q) {
            int s = (int)(unsigned)(rec[q] & 0xffffffffu);
            raw[q] = *(const unsigned*)&A2[(size_t)s * 32 + l];
        }
#pragma unroll
        for (int q = 0; q < 8; ++q) {
            float w = __uint_as_float((unsigned)(rec[q] >> 32));
            float2 v = __half22float2(*(__half2*)&raw[q]);
            acc.x += w * v.x;
            acc.y += w * v.y;
        }
    }
    if (jb < c) {                                      // tail: clamped
        int cm1 = c - 1;
        u64 myrec = ed[min(jb + (lane & 15), cm1)];
        u64 rec[8];
#pragma unroll
        for (int q = 0; q < 8; ++q) rec[q] = __shfl(myrec, 2 * q + g);
        unsigned raw[8];
#pragma unroll
        for (int q = 0; q < 8; ++q) {
            int s = (int)(unsigned)(rec[q] & 0xffffffffu);
            raw[q] = *(const unsigned*)&A2[(size_t)s * 32 + l];
        }
#pragma unroll
        for (int q = 0; q < 8; ++q) {
            int idx = jb + 2 * q + g;
            float w = (idx < c) ? __uint_as_float((unsigned)(rec[q] >> 32)) : 0.f;
            float2 v = __half22float2(*(__half2*)&raw[q]);
            acc.x += w * v.x;
            acc.y += w * v.y;
        }
    }
    acc.x += __shfl_xor(acc.x, 32);
    acc.y += __shfl_xor(acc.y, 32);
    return acc;
}

// ---------------- layer-1 aggregate + self-loop + bias + ReLU ----------------
__global__ __launch_bounds__(256) void k_agg1(
    const __half* __restrict__ A, const int* __restrict__ rowptr, const int* __restrict__ cnt,
    const u64* __restrict__ edat, const float* __restrict__ deg,
    const float* __restrict__ b1, float* __restrict__ H, int N)
{
    int node = blockIdx.x * 4 + (threadIdx.x >> 6);
    if (node >= N) return;
    int lane = threadIdx.x & 63;
    int l = lane & 31;
    const __half2* A2 = (const __half2*)A;
    float2 acc = agg_node2(A2, edat + rowptr[node], cnt[node], lane);
    float dsd = rsqrtf(deg[node]);
    float2 self = __half22float2(A2[(size_t)node * 32 + l]);
    float2 bb = ((const float2*)b1)[l];
    if (lane < 32) {
        float2 h;
        h.x = fmaxf(dsd * (acc.x + self.x) + bb.x, 0.f);
        h.y = fmaxf(dsd * (acc.y + self.y) + bb.y, 0.f);
        ((float2*)(H + (size_t)node * 64))[l] = h;
    }
}

// ---------------- layer-2 aggregate fused with classifier + softmax ----------------
__global__ __launch_bounds__(256) void k_agg2_final(
    const __half* __restrict__ A, const int* __restrict__ rowptr, const int* __restrict__ cnt,
    const u64* __restrict__ edat, const float* __restrict__ deg,
    const float* __restrict__ b2, const float* __restrict__ labels,
    const float* __restrict__ Wc, const float* __restrict__ bc,
    float* __restrict__ out, int N)
{
    int node = blockIdx.x * 4 + (threadIdx.x >> 6);
    if (node >= N) return;
    int lane = threadIdx.x & 63;
    int l = lane & 31;
    const __half2* A2 = (const __half2*)A;
    float2 acc = agg_node2(A2, edat + rowptr[node], cnt[node], lane);
    float dsd = rsqrtf(deg[node]);
    float2 self = __half22float2(A2[(size_t)node * 32 + l]);
    float2 bb = ((const float2*)b2)[l];
    float hx = dsd * (acc.x + self.x) + bb.x;
    float hy = dsd * (acc.y + self.y) + bb.y;
    float2 wc0 = ((const float2*)Wc)[l];
    float w1x = Wc[65 + 2 * l], w1y = Wc[65 + 2 * l + 1];
    float p0 = hx * wc0.x + hy * wc0.y;
    float p1 = hx * w1x + hy * w1y;
    if (lane >= 32) { p0 = 0.f; p1 = 0.f; }   // halves duplicated post-combine
#pragma unroll
    for (int mm = 1; mm < 64; mm <<= 1) {
        p0 += __shfl_xor(p0, mm);
        p1 += __shfl_xor(p1, mm);
    }
    if (lane == 0) {
        float lab = labels[node];
        float l0 = p0 + lab * Wc[64] + bc[0];
        float l1 = p1 + lab * Wc[65 + 64] + bc[1];
        float mx = fmaxf(l0, l1);
        float e0 = expf(l0 - mx), e1 = expf(l1 - mx);
        float inv = 1.0f / (e0 + e1);
        out[2 * (size_t)node]     = e0 * inv;
        out[2 * (size_t)node + 1] = e1 * inv;
    }
}

extern "C" void kernel_launch(void* const* d_in, const int* in_sizes, int n_in,
                              void* d_out, int out_size, void* d_ws, size_t ws_size,
                              hipStream_t stream)
{
    const float* emb      = (const float*)d_in[0];
    const float* features = (const float*)d_in[1];
    const float* labels   = (const float*)d_in[2];
    const float* Wv       = (const float*)d_in[3];
    const float* bv       = (const float*)d_in[4];
    const float* W1       = (const float*)d_in[5];
    const float* b1       = (const float*)d_in[6];
    const float* W2       = (const float*)d_in[7];
    const float* b2       = (const float*)d_in[8];
    const float* Wc       = (const float*)d_in[9];
    const float* bc       = (const float*)d_in[10];
    const int*   eidx     = (const int*)d_in[11];

    const int E = in_sizes[11] / 2;   // 1600000
    const int N = in_sizes[1] / 64;   // 100000
    const int* src = eidx;
    const int* dst = eidx + E;

    float* out      = (float*)d_out;
    float* out_sens = out;                  // N*2
    float* out_ew   = out + 2 * (size_t)N;  // E

    const int nbk  = (N + BSZ - 1) >> SHIFT;       // 98
    const int nblk = (E + EPB - 1) / EPB;          // 391

    // workspace layout (4B units, u64 regions 8B aligned):
    float*  deg    = (float*)d_ws;
    __half* Ah     = (__half*)(deg + N);
    float*  H      = (float*)(Ah + (size_t)N * 64);
    int*    cnt    = (int*)(H + (size_t)N * 64);
    int*    rowptr = cnt + N;
    int*    ghist  = rowptr + N;
    int*    btot   = ghist + (size_t)nbk * nblk;
    int*    bstart = btot + nbk;
    int*    endi   = bstart + ((nbk + 2) & ~1);
    u64*    tmp    = (u64*)((((size_t)(endi - (int*)d_ws)) + 1 & ~(size_t)1) * 4 + (char*)d_ws);
    u64*    edat   = tmp + E;

    // pure streaming pass
    k_edge_ew<<<(E / 4 + 7) / 8, 256, 0, stream>>>(emb, Wv, bv, out_ew, E);

    // radix CSR build — zero random global atomics
    k_hist<<<nblk, 256, 0, stream>>>(dst, ghist, E, nbk, nblk);
    k_scan_col<<<nbk, 512, 0, stream>>>(ghist, btot, nblk);
    k_scan_tot<<<1, 64, 0, stream>>>(btot, bstart, nbk);
    k_scatter<<<nblk, 256, 0, stream>>>(src, dst, out_ew, ghist, bstart, tmp, E, nbk, nblk);
    k_build<<<nbk, 512, 0, stream>>>(tmp, bstart, edat, rowptr, cnt, deg, N);

    // layer 1
    k_gemm64h<<<(N + 255) / 256, 256, 0, stream>>>(features, W1, deg, Ah, N);
    k_agg1<<<(N + 3) / 4, 256, 0, stream>>>(Ah, rowptr, cnt, edat, deg, b1, H, N);

    // layer 2 + classifier + softmax
    k_gemm64h<<<(N + 255) / 256, 256, 0, stream>>>(H, W2, deg, Ah, N);
    k_agg2_final<<<(N + 3) / 4, 256, 0, stream>>>(Ah, rowptr, cnt, edat, deg, b2,
                                                  labels, Wc, bc, out_sens, N);
}